// Round 14
// baseline (96.672 us; speedup 1.0000x reference)
//
#include <hip/hip_runtime.h>
#include <hip/hip_bf16.h>
#include <stdint.h>

#define M_DIM 2048
#define N_DIM 4096
#define K_DIM 4096

#define NT 64  // K tiles of 64

typedef short short8 __attribute__((ext_vector_type(8)));
typedef float f32x4 __attribute__((ext_vector_type(4)));

typedef __attribute__((address_space(1))) unsigned int gu32;
typedef __attribute__((address_space(3))) unsigned int lu32;

// f32 -> bf16 round-to-nearest-even
__device__ static inline unsigned short f32_to_bf16(float f) {
  union { float f; unsigned int u; } v; v.f = f;
  unsigned int u = v.u;
  u += 0x7FFFu + ((u >> 16) & 1u);
  return (unsigned short)(u >> 16);
}

__device__ static inline short8 cvt8(f32x4 a, f32x4 b) {
  short8 o;
  o[0] = (short)f32_to_bf16(a[0]); o[1] = (short)f32_to_bf16(a[1]);
  o[2] = (short)f32_to_bf16(a[2]); o[3] = (short)f32_to_bf16(a[3]);
  o[4] = (short)f32_to_bf16(b[0]); o[5] = (short)f32_to_bf16(b[1]);
  o[6] = (short)f32_to_bf16(b[2]); o[7] = (short)f32_to_bf16(b[3]);
  return o;
}

// ---- prep (w only now): f32 [K][N] -> bf16 Bt [N][K] via 64x64 LDS tile ----
__global__ void prep_kernel(const float* __restrict__ wsrc, unsigned short* __restrict__ wt) {
  __shared__ unsigned short tile[64][64 + 8];
  int b2 = blockIdx.x;
  int t = threadIdx.x;
  int bn = (b2 & 63) * 64;  // n block
  int bk = (b2 >> 6) * 64;  // k block
  int c4 = (t & 15) * 4;
  int r0 = t >> 4;
#pragma unroll
  for (int p = 0; p < 4; ++p) {
    int r = r0 + p * 16;
    f32x4 v = *(const f32x4*)(wsrc + (size_t)(bk + r) * N_DIM + bn + c4);
    tile[c4 + 0][r] = f32_to_bf16(v[0]);
    tile[c4 + 1][r] = f32_to_bf16(v[1]);
    tile[c4 + 2][r] = f32_to_bf16(v[2]);
    tile[c4 + 3][r] = f32_to_bf16(v[3]);
  }
  __syncthreads();
  int orow = t >> 2;
  int oc = (t & 3) * 16;
  short8 lo, hi;
#pragma unroll
  for (int j = 0; j < 8; ++j) {
    lo[j] = (short)tile[orow][oc + j];
    hi[j] = (short)tile[orow][oc + 8 + j];
  }
  unsigned short* op = wt + (size_t)(bn + orow) * K_DIM + bk + oc;
  *(short8*)(op) = lo;
  *(short8*)(op + 8) = hi;
}

// ==== GEMM (round 14): R13 body + in-kernel A f32->bf16 staging ====
// BM=128, BN=256, BK=64. 512 threads = 8 waves (2M x 4N), wave tile 64x64.
// LDS: 3 sides x 48KB; side t%3; stage t+2 into (t-1)%3 during body t.
// A is staged from x (f32, L3-resident) via registers: load 4x f32x4,
// cvt to bf16 (~64 VALU, overlaps MFMA pipe per m114), ds_write_b128 to the
// SAME swizzled layout global_load_lds wrote (wave-uniform base + lane*16).
// This deletes the 48MB x-cvt pass from prep (prep = w-only, 96MB).
// B staging unchanged: 4 global_load_lds per thread per tile.
// Sync proof (vmcnt = in-order FIFO, m135): body t issues [A-f32 x4,
// B-GL x4] for t+2. Compiler's wait before the cvt uses must retire the
// youngest A loads => retires all older ops incl. B(t) => manual top-of-
// tile vmcnt(4) suffices under ANY compiler ordering (tail: vmcnt(0)).
// A(t+2) ds_writes publish via top-of-(t+1) lgkmcnt(0)+barrier; read at
// body t+2 (two barriers later). WAR on side (t-1)%3: writes occur after
// top-of-t barrier, whose lgkmcnt(0) drained all waves' t-1 reads.

__global__ __launch_bounds__(512) void gemm8_kernel(
    const float* __restrict__ Xf, const unsigned short* __restrict__ Bt,
    const float* __restrict__ bias, float* __restrict__ C) {
  __shared__ unsigned short smA[3 * 24576];  // 147456 B
  char* smemc = (char*)&smA[0];

  const int tid = threadIdx.x;
  const int lane = tid & 63;
  const int w = tid >> 6;
  const int wm = w >> 2, wn = w & 3;

  // 8x4 region remap for L2 locality (bijective over 256 blocks)
  const int id = blockIdx.x;
  const int x = id & 7, j = id >> 3;
  const int by = ((x >> 2) << 3) + (j >> 2);
  const int bx = ((x & 3) << 2) + (j & 3);
  const int r0 = by * 128, c0 = bx * 256;

  // ---- staging precompute ----
  const int l8 = lane >> 3, l7 = lane & 7;
  const int chunkE = ((l7 ^ l8) << 3);  // swizzled k-chunk (elem index), row&7 == l8
  const float* Axf = Xf + (size_t)(r0 + w * 16 + l8) * K_DIM + chunkE;  // f32 source
  const unsigned short* Bg = Bt + (size_t)(c0 + w * 32 + l8) * K_DIM + chunkE;
  const int aL0 = w * 2048 + lane * 16;  // this lane's A write offset within side
  const int bL0 = 16384 + w * 4096;      // wave's B chunk base within side

#define GL(gp, ldsoff) __builtin_amdgcn_global_load_lds((gu32*)(gp), (lu32*)(smemc + (ldsoff)), 16, 0, 0)
#define STAGE_B(t, sb)                                                 \
  do {                                                                 \
    GL(Bg + (size_t)(t) * 64, (sb) + bL0);                             \
    GL(Bg + (size_t)(t) * 64 + 8 * (size_t)K_DIM, (sb) + bL0 + 1024);  \
    GL(Bg + (size_t)(t) * 64 + 16 * (size_t)K_DIM, (sb) + bL0 + 2048); \
    GL(Bg + (size_t)(t) * 64 + 24 * (size_t)K_DIM, (sb) + bL0 + 3072); \
  } while (0)

  // ---- fragment-read precompute (ushort units within side) ----
  const int l15 = lane & 15, hi = lane >> 4;
  const int aR = (wm * 64 + l15) * 64;         // A row base
  const int bR = 8192 + (wn * 64 + l15) * 64;  // B row base (B region at 16KB)
  const int slot0 = ((hi ^ l7) << 3);          // ks=0: chunk hi at slot hi^(row&7)
  const int slot1 = (((4 + hi) ^ l7) << 3);    // ks=1: chunk 4+hi

  f32x4 acc[4][4] = {};

  // ---- prologue: A(0)->side0, A(1)->side1 (reg path); B(0), B(1) GLs ----
  {
    f32x4 v0 = *(const f32x4*)(Axf);
    f32x4 v1 = *(const f32x4*)(Axf + 4);
    f32x4 v2 = *(const f32x4*)(Axf + 8 * (size_t)K_DIM);
    f32x4 v3 = *(const f32x4*)(Axf + 8 * (size_t)K_DIM + 4);
    *(short8*)(smemc + 0 + aL0) = cvt8(v0, v1);
    *(short8*)(smemc + 0 + aL0 + 1024) = cvt8(v2, v3);
    f32x4 u0 = *(const f32x4*)(Axf + 64);
    f32x4 u1 = *(const f32x4*)(Axf + 64 + 4);
    f32x4 u2 = *(const f32x4*)(Axf + 64 + 8 * (size_t)K_DIM);
    f32x4 u3 = *(const f32x4*)(Axf + 64 + 8 * (size_t)K_DIM + 4);
    *(short8*)(smemc + 49152 + aL0) = cvt8(u0, u1);
    *(short8*)(smemc + 49152 + aL0 + 1024) = cvt8(u2, u3);
  }
  STAGE_B(0, 0);
  STAGE_B(1, 49152);

  int cs = 0;  // side of tile t
  for (int t = 0; t < NT; ++t) {
    const int sE = cs * 24576;                       // compute side (ushorts)
    const int stB = (cs == 0 ? 2 : cs - 1) * 49152;  // stage side (bytes)
    const bool doStage = (t + 2) < NT;

    // top sync: B(t) retired (in-order FIFO: compiler's A-cvt wait in body
    // t-1 retired everything older than A(t+1), incl. B(t); vmcnt(4) keeps
    // at most B(t+2)-age ops in flight), my t-1 LDS ops drained, publish.
    if (t < NT - 1) asm volatile("s_waitcnt vmcnt(4) lgkmcnt(0)" ::: "memory");
    else            asm volatile("s_waitcnt vmcnt(0) lgkmcnt(0)" ::: "memory");
    __builtin_amdgcn_sched_barrier(0);
    asm volatile("s_barrier" ::: "memory");

    // -------- merged body --------
    short8 a0[4], b0[4], a1[4], b1[4];
#pragma unroll
    for (int m = 0; m < 4; ++m) a0[m] = *(const short8*)(smA + sE + aR + m * 1024 + slot0);
#pragma unroll
    for (int n = 0; n < 4; ++n) b0[n] = *(const short8*)(smA + sE + bR + n * 1024 + slot0);

    f32x4 av0, av1, av2, av3;
    if (doStage) {
      av0 = *(const f32x4*)(Axf + (size_t)(t + 2) * 64);
      av1 = *(const f32x4*)(Axf + (size_t)(t + 2) * 64 + 4);
      av2 = *(const f32x4*)(Axf + (size_t)(t + 2) * 64 + 8 * (size_t)K_DIM);
      av3 = *(const f32x4*)(Axf + (size_t)(t + 2) * 64 + 8 * (size_t)K_DIM + 4);
      STAGE_B(t + 2, stB);
    }

#pragma unroll
    for (int m = 0; m < 4; ++m) a1[m] = *(const short8*)(smA + sE + aR + m * 1024 + slot1);
#pragma unroll
    for (int n = 0; n < 4; ++n) b1[n] = *(const short8*)(smA + sE + bR + n * 1024 + slot1);

#pragma unroll
    for (int m = 0; m < 4; ++m)
#pragma unroll
      for (int n = 0; n < 4; ++n)
        acc[m][n] = __builtin_amdgcn_mfma_f32_16x16x32_bf16(a0[m], b0[n], acc[m][n], 0, 0, 0);

    if (doStage) {
      *(short8*)(smemc + stB + aL0) = cvt8(av0, av1);
      *(short8*)(smemc + stB + aL0 + 1024) = cvt8(av2, av3);
    }

#pragma unroll
    for (int m = 0; m < 4; ++m)
#pragma unroll
      for (int n = 0; n < 4; ++n)
        acc[m][n] = __builtin_amdgcn_mfma_f32_16x16x32_bf16(a1[m], b1[n], acc[m][n], 0, 0, 0);

    cs = (cs == 2) ? 0 : cs + 1;
  }

  // ---- epilogue: fxp(y) + fxp(b), relu ----
  const float S = 65536.0f, IS = 1.0f / 65536.0f;
  const int lr = hi * 4;  // C/D: row=(lane>>4)*4+reg, col=lane&15
#pragma unroll
  for (int n = 0; n < 4; ++n) {
    int gcol = c0 + wn * 64 + n * 16 + l15;
    float bq = rintf(bias[gcol] * S) * IS;
#pragma unroll
    for (int m = 0; m < 4; ++m) {
      int grow = r0 + wm * 64 + m * 16 + lr;
      float* outp = C + (size_t)grow * N_DIM + gcol;
#pragma unroll
      for (int r = 0; r < 4; ++r) {
        float t = rintf(acc[m][n][r] * S) * IS + bq;
        t = t > 0.0f ? t : 0.0f;
        outp[(size_t)r * N_DIM] = t;
      }
    }
  }
#undef GL
#undef STAGE_B
}

// ---- fallback (small workspace): round-1 reg-staged kernel ----
__global__ __launch_bounds__(256, 2) void gemm_fb_kernel(
    const float* __restrict__ Xf, const float* __restrict__ Wf,
    const float* __restrict__ bias, float* __restrict__ C) {
  __shared__ unsigned short As[128][64];
  __shared__ unsigned short Bs[128][64];
  int tid = threadIdx.x;
  int lane = tid & 63;
  int wid = tid >> 6;
  int wr = wid >> 1, wc = wid & 1;
  int r0 = blockIdx.y * 128;
  int c0 = blockIdx.x * 128;
  f32x4 acc[4][4] = {};
  for (int kt = 0; kt < K_DIM / 64; ++kt) {
    __syncthreads();
    int ar = tid >> 1;
    int ac = (tid & 1) * 32;
    const float* xp = Xf + (size_t)(r0 + ar) * K_DIM + kt * 64 + ac;
#pragma unroll
    for (int jj = 0; jj < 8; ++jj) {
      f32x4 v = *(const f32x4*)(xp + jj * 4);
      As[ar][ac + jj * 4 + 0] = f32_to_bf16(v[0]);
      As[ar][ac + jj * 4 + 1] = f32_to_bf16(v[1]);
      As[ar][ac + jj * 4 + 2] = f32_to_bf16(v[2]);
      As[ar][ac + jj * 4 + 3] = f32_to_bf16(v[3]);
    }
    int bk_ = tid >> 2;
    int bc = (tid & 3) * 32;
    const float* wp = Wf + (size_t)(kt * 64 + bk_) * N_DIM + c0 + bc;
#pragma unroll
    for (int jj = 0; jj < 8; ++jj) {
      f32x4 v = *(const f32x4*)(wp + jj * 4);
      Bs[bc + jj * 4 + 0][bk_] = f32_to_bf16(v[0]);
      Bs[bc + jj * 4 + 1][bk_] = f32_to_bf16(v[1]);
      Bs[bc + jj * 4 + 2][bk_] = f32_to_bf16(v[2]);
      Bs[bc + jj * 4 + 3][bk_] = f32_to_bf16(v[3]);
    }
    __syncthreads();
#pragma unroll
    for (int ks = 0; ks < 2; ++ks) {
      int co = ks * 32 + (lane >> 4) * 8;
      int rA = wr * 64 + (lane & 15);
      int rB = wc * 64 + (lane & 15);
      short8 a[4], b[4];
#pragma unroll
      for (int m = 0; m < 4; ++m) a[m] = *(const short8*)&As[rA + m * 16][co];
#pragma unroll
      for (int n = 0; n < 4; ++n) b[n] = *(const short8*)&Bs[rB + n * 16][co];
#pragma unroll
      for (int m = 0; m < 4; ++m)
#pragma unroll
        for (int n = 0; n < 4; ++n)
          acc[m][n] = __builtin_amdgcn_mfma_f32_16x16x32_bf16(a[m], b[n], acc[m][n], 0, 0, 0);
    }
  }
  const float S = 65536.0f, IS = 1.0f / 65536.0f;
  int lr = (lane >> 4) * 4;
  int lc = lane & 15;
#pragma unroll
  for (int n = 0; n < 4; ++n) {
    int gcol = c0 + wc * 64 + n * 16 + lc;
    float bq = rintf(bias[gcol] * S) * IS;
#pragma unroll
    for (int m = 0; m < 4; ++m) {
      int grow = r0 + wr * 64 + m * 16 + lr;
      float* outp = C + (size_t)grow * N_DIM + gcol;
#pragma unroll
      for (int r = 0; r < 4; ++r) {
        float t = rintf(acc[m][n][r] * S) * IS + bq;
        t = t > 0.0f ? t : 0.0f;
        outp[(size_t)r * N_DIM] = t;
      }
    }
  }
}

extern "C" void kernel_launch(void* const* d_in, const int* in_sizes, int n_in,
                              void* d_out, int out_size, void* d_ws, size_t ws_size,
                              hipStream_t stream) {
  const float* x = (const float*)d_in[0];
  const float* w = (const float*)d_in[1];
  const float* b = (const float*)d_in[2];
  float* out = (float*)d_out;

  size_t needB = (size_t)K_DIM * N_DIM * sizeof(unsigned short);

  if (ws_size >= needB) {
    unsigned short* Btbf = (unsigned short*)d_ws;
    prep_kernel<<<4096, 256, 0, stream>>>(w, Btbf);
    gemm8_kernel<<<256, 512, 0, stream>>>(x, Btbf, b, out);
  } else {
    gemm_fb_kernel<<<dim3(N_DIM / 128, M_DIM / 128), 256, 0, stream>>>(x, w, b, out);
  }
}

// Round 15
// 96.590 us; speedup vs baseline: 1.0008x; 1.0008x over previous
//
#include <hip/hip_runtime.h>
#include <hip/hip_bf16.h>
#include <stdint.h>

#define M_DIM 2048
#define N_DIM 4096
#define K_DIM 4096

#define NT 64  // K tiles of 64

typedef short short8 __attribute__((ext_vector_type(8)));
typedef float f32x4 __attribute__((ext_vector_type(4)));

typedef __attribute__((address_space(1))) unsigned int gu32;
typedef __attribute__((address_space(3))) unsigned int lu32;

// f32 -> bf16 round-to-nearest-even
__device__ static inline unsigned short f32_to_bf16(float f) {
  union { float f; unsigned int u; } v; v.f = f;
  unsigned int u = v.u;
  u += 0x7FFFu + ((u >> 16) & 1u);
  return (unsigned short)(u >> 16);
}

__device__ static inline short8 cvt8(f32x4 a, f32x4 b) {
  short8 o;
  o[0] = (short)f32_to_bf16(a[0]); o[1] = (short)f32_to_bf16(a[1]);
  o[2] = (short)f32_to_bf16(a[2]); o[3] = (short)f32_to_bf16(a[3]);
  o[4] = (short)f32_to_bf16(b[0]); o[5] = (short)f32_to_bf16(b[1]);
  o[6] = (short)f32_to_bf16(b[2]); o[7] = (short)f32_to_bf16(b[3]);
  return o;
}

// ---- prep (w only): f32 [K][N] -> bf16 Bt [N][K] via 64x64 LDS tile ----
__global__ void prep_kernel(const float* __restrict__ wsrc, unsigned short* __restrict__ wt) {
  __shared__ unsigned short tile[64][64 + 8];
  int b2 = blockIdx.x;
  int t = threadIdx.x;
  int bn = (b2 & 63) * 64;  // n block
  int bk = (b2 >> 6) * 64;  // k block
  int c4 = (t & 15) * 4;
  int r0 = t >> 4;
#pragma unroll
  for (int p = 0; p < 4; ++p) {
    int r = r0 + p * 16;
    f32x4 v = *(const f32x4*)(wsrc + (size_t)(bk + r) * N_DIM + bn + c4);
    tile[c4 + 0][r] = f32_to_bf16(v[0]);
    tile[c4 + 1][r] = f32_to_bf16(v[1]);
    tile[c4 + 2][r] = f32_to_bf16(v[2]);
    tile[c4 + 3][r] = f32_to_bf16(v[3]);
  }
  __syncthreads();
  int orow = t >> 2;
  int oc = (t & 3) * 16;
  short8 lo, hi;
#pragma unroll
  for (int j = 0; j < 8; ++j) {
    lo[j] = (short)tile[orow][oc + j];
    hi[j] = (short)tile[orow][oc + 8 + j];
  }
  unsigned short* op = wt + (size_t)(bn + orow) * K_DIM + bk + oc;
  *(short8*)(op) = lo;
  *(short8*)(op + 8) = hi;
}

// ==== GEMM (round 15): R13 body + PIPELINED in-kernel A f32->bf16 ====
// BM=128, BN=256, BK=64. 512 threads = 8 waves (2M x 4N), wave tile 64x64.
// LDS: 3 sides x 48KB; side t%3; stage t+2 into (t-1)%3 during body t.
// R14's bug: A-f32 loads issued AND consumed in body t => compiler's vmcnt
// wait mid-body exposed ~500-900cyc L3 latency/tile (+1600 cyc measured).
// Fix: body t consumes A-f32(t+2) loaded in body t-1 (>=2000cyc distance);
// issues A-f32(t+3) early. cvt+ds_write placed between MFMA halves; target
// side (t+2)%3 = same side/timing as B staging (WAR proof unchanged: that
// side's readers drained at top-of-t lgkmcnt(0)+barrier).
// FIFO audit at top-of-t (oldest->newest): [A(t+1): already retired by
// body t-1's cvt wait][B(t)x4][A(t+2)x4][B(t+1)x4] => vmcnt(8) retires
// exactly B(t). Tail: t=NT-2 -> vmcnt(4) (no A(NT) issued); NT-1 -> 0.
// A-layout (wave-uniform base + lane*16, swizzled source) correctness-
// proven by R14 (passed, absmax 0.03125).

__global__ __launch_bounds__(512) void gemm8_kernel(
    const float* __restrict__ Xf, const unsigned short* __restrict__ Bt,
    const float* __restrict__ bias, float* __restrict__ C) {
  __shared__ unsigned short smA[3 * 24576];  // 147456 B
  char* smemc = (char*)&smA[0];

  const int tid = threadIdx.x;
  const int lane = tid & 63;
  const int w = tid >> 6;
  const int wm = w >> 2, wn = w & 3;

  // 8x4 region remap for L2 locality (bijective over 256 blocks)
  const int id = blockIdx.x;
  const int x = id & 7, j = id >> 3;
  const int by = ((x >> 2) << 3) + (j >> 2);
  const int bx = ((x & 3) << 2) + (j & 3);
  const int r0 = by * 128, c0 = bx * 256;

  // ---- staging precompute ----
  const int l8 = lane >> 3, l7 = lane & 7;
  const int chunkE = ((l7 ^ l8) << 3);  // swizzled k-chunk (elem idx), row&7 == l8
  const float* Axf = Xf + (size_t)(r0 + w * 16 + l8) * K_DIM + chunkE;  // f32 source
  const unsigned short* Bg = Bt + (size_t)(c0 + w * 32 + l8) * K_DIM + chunkE;
  const int aL0 = w * 2048 + lane * 16;  // this lane's A write offset within side
  const int bL0 = 16384 + w * 4096;      // wave's B chunk base within side

#define GL(gp, ldsoff) __builtin_amdgcn_global_load_lds((gu32*)(gp), (lu32*)(smemc + (ldsoff)), 16, 0, 0)
#define STAGE_B(t, sb)                                                 \
  do {                                                                 \
    GL(Bg + (size_t)(t) * 64, (sb) + bL0);                             \
    GL(Bg + (size_t)(t) * 64 + 8 * (size_t)K_DIM, (sb) + bL0 + 1024);  \
    GL(Bg + (size_t)(t) * 64 + 16 * (size_t)K_DIM, (sb) + bL0 + 2048); \
    GL(Bg + (size_t)(t) * 64 + 24 * (size_t)K_DIM, (sb) + bL0 + 3072); \
  } while (0)
#define LOADA(T)                                                       \
  do {                                                                 \
    av0 = *(const f32x4*)(Axf + (size_t)(T) * 64);                     \
    av1 = *(const f32x4*)(Axf + (size_t)(T) * 64 + 4);                 \
    av2 = *(const f32x4*)(Axf + (size_t)(T) * 64 + 8 * (size_t)K_DIM); \
    av3 = *(const f32x4*)(Axf + (size_t)(T) * 64 + 8 * (size_t)K_DIM + 4); \
  } while (0)

  // ---- fragment-read precompute (ushort units within side) ----
  const int l15 = lane & 15, hi = lane >> 4;
  const int aR = (wm * 64 + l15) * 64;         // A row base
  const int bR = 8192 + (wn * 64 + l15) * 64;  // B row base (B region at 16KB)
  const int slot0 = ((hi ^ l7) << 3);          // ks=0: chunk hi at slot hi^(row&7)
  const int slot1 = (((4 + hi) ^ l7) << 3);    // ks=1: chunk 4+hi

  f32x4 acc[4][4] = {};
  f32x4 av0, av1, av2, av3;  // pipelined A f32 regs (tile t+2 during body t)

  // ---- prologue ----
  {
    // A(0)->side0, A(1)->side1 directly
    f32x4 p0 = *(const f32x4*)(Axf);
    f32x4 p1 = *(const f32x4*)(Axf + 4);
    f32x4 p2 = *(const f32x4*)(Axf + 8 * (size_t)K_DIM);
    f32x4 p3 = *(const f32x4*)(Axf + 8 * (size_t)K_DIM + 4);
    *(short8*)(smemc + 0 + aL0) = cvt8(p0, p1);
    *(short8*)(smemc + 0 + aL0 + 1024) = cvt8(p2, p3);
    f32x4 q0 = *(const f32x4*)(Axf + 64);
    f32x4 q1 = *(const f32x4*)(Axf + 64 + 4);
    f32x4 q2 = *(const f32x4*)(Axf + 64 + 8 * (size_t)K_DIM);
    f32x4 q3 = *(const f32x4*)(Axf + 64 + 8 * (size_t)K_DIM + 4);
    *(short8*)(smemc + 49152 + aL0) = cvt8(q0, q1);
    *(short8*)(smemc + 49152 + aL0 + 1024) = cvt8(q2, q3);
  }
  STAGE_B(0, 0);
  STAGE_B(1, 49152);
  LOADA(2);  // consumed in body 0

  int cs = 0;  // side of tile t
  for (int t = 0; t < NT; ++t) {
    const int sE = cs * 24576;                       // compute side (ushorts)
    const int stB = (cs == 0 ? 2 : cs - 1) * 49152;  // stage side (bytes)

    // top sync (FIFO audit in header): retire B(t), keep A(t+2)+B(t+1)
    if (t < NT - 2)      asm volatile("s_waitcnt vmcnt(8) lgkmcnt(0)" ::: "memory");
    else if (t < NT - 1) asm volatile("s_waitcnt vmcnt(4) lgkmcnt(0)" ::: "memory");
    else                 asm volatile("s_waitcnt vmcnt(0) lgkmcnt(0)" ::: "memory");
    __builtin_amdgcn_sched_barrier(0);
    asm volatile("s_barrier" ::: "memory");

    // -------- merged body --------
    short8 a0[4], b0[4], a1[4], b1[4];
#pragma unroll
    for (int m = 0; m < 4; ++m) a0[m] = *(const short8*)(smA + sE + aR + m * 1024 + slot0);
#pragma unroll
    for (int n = 0; n < 4; ++n) b0[n] = *(const short8*)(smA + sE + bR + n * 1024 + slot0);

    // capture this body's A-f32 (loaded last body), then issue next loads
    f32x4 c0v = av0, c1v = av1, c2v = av2, c3v = av3;
    if (t + 3 < NT) LOADA(t + 3);
    if (t + 2 < NT) STAGE_B(t + 2, stB);

#pragma unroll
    for (int m = 0; m < 4; ++m) a1[m] = *(const short8*)(smA + sE + aR + m * 1024 + slot1);
#pragma unroll
    for (int n = 0; n < 4; ++n) b1[n] = *(const short8*)(smA + sE + bR + n * 1024 + slot1);

#pragma unroll
    for (int m = 0; m < 4; ++m)
#pragma unroll
      for (int n = 0; n < 4; ++n)
        acc[m][n] = __builtin_amdgcn_mfma_f32_16x16x32_bf16(a0[m], b0[n], acc[m][n], 0, 0, 0);

    if (t + 2 < NT) {  // cvt+write A(t+2), loaded a full body ago
      *(short8*)(smemc + stB + aL0) = cvt8(c0v, c1v);
      *(short8*)(smemc + stB + aL0 + 1024) = cvt8(c2v, c3v);
    }

#pragma unroll
    for (int m = 0; m < 4; ++m)
#pragma unroll
      for (int n = 0; n < 4; ++n)
        acc[m][n] = __builtin_amdgcn_mfma_f32_16x16x32_bf16(a1[m], b1[n], acc[m][n], 0, 0, 0);

    cs = (cs == 2) ? 0 : cs + 1;
  }

  // ---- epilogue: fxp(y) + fxp(b), relu ----
  const float S = 65536.0f, IS = 1.0f / 65536.0f;
  const int lr = hi * 4;  // C/D: row=(lane>>4)*4+reg, col=lane&15
#pragma unroll
  for (int n = 0; n < 4; ++n) {
    int gcol = c0 + wn * 64 + n * 16 + l15;
    float bq = rintf(bias[gcol] * S) * IS;
#pragma unroll
    for (int m = 0; m < 4; ++m) {
      int grow = r0 + wm * 64 + m * 16 + lr;
      float* outp = C + (size_t)grow * N_DIM + gcol;
#pragma unroll
      for (int r = 0; r < 4; ++r) {
        float t = rintf(acc[m][n][r] * S) * IS + bq;
        t = t > 0.0f ? t : 0.0f;
        outp[(size_t)r * N_DIM] = t;
      }
    }
  }
#undef GL
#undef STAGE_B
#undef LOADA
}

// ---- fallback (small workspace): round-1 reg-staged kernel ----
__global__ __launch_bounds__(256, 2) void gemm_fb_kernel(
    const float* __restrict__ Xf, const float* __restrict__ Wf,
    const float* __restrict__ bias, float* __restrict__ C) {
  __shared__ unsigned short As[128][64];
  __shared__ unsigned short Bs[128][64];
  int tid = threadIdx.x;
  int lane = tid & 63;
  int wid = tid >> 6;
  int wr = wid >> 1, wc = wid & 1;
  int r0 = blockIdx.y * 128;
  int c0 = blockIdx.x * 128;
  f32x4 acc[4][4] = {};
  for (int kt = 0; kt < K_DIM / 64; ++kt) {
    __syncthreads();
    int ar = tid >> 1;
    int ac = (tid & 1) * 32;
    const float* xp = Xf + (size_t)(r0 + ar) * K_DIM + kt * 64 + ac;
#pragma unroll
    for (int jj = 0; jj < 8; ++jj) {
      f32x4 v = *(const f32x4*)(xp + jj * 4);
      As[ar][ac + jj * 4 + 0] = f32_to_bf16(v[0]);
      As[ar][ac + jj * 4 + 1] = f32_to_bf16(v[1]);
      As[ar][ac + jj * 4 + 2] = f32_to_bf16(v[2]);
      As[ar][ac + jj * 4 + 3] = f32_to_bf16(v[3]);
    }
    int bk_ = tid >> 2;
    int bc = (tid & 3) * 32;
    const float* wp = Wf + (size_t)(kt * 64 + bk_) * N_DIM + c0 + bc;
#pragma unroll
    for (int jj = 0; jj < 8; ++jj) {
      f32x4 v = *(const f32x4*)(wp + jj * 4);
      Bs[bc + jj * 4 + 0][bk_] = f32_to_bf16(v[0]);
      Bs[bc + jj * 4 + 1][bk_] = f32_to_bf16(v[1]);
      Bs[bc + jj * 4 + 2][bk_] = f32_to_bf16(v[2]);
      Bs[bc + jj * 4 + 3][bk_] = f32_to_bf16(v[3]);
    }
    __syncthreads();
#pragma unroll
    for (int ks = 0; ks < 2; ++ks) {
      int co = ks * 32 + (lane >> 4) * 8;
      int rA = wr * 64 + (lane & 15);
      int rB = wc * 64 + (lane & 15);
      short8 a[4], b[4];
#pragma unroll
      for (int m = 0; m < 4; ++m) a[m] = *(const short8*)&As[rA + m * 16][co];
#pragma unroll
      for (int n = 0; n < 4; ++n) b[n] = *(const short8*)&Bs[rB + n * 16][co];
#pragma unroll
      for (int m = 0; m < 4; ++m)
#pragma unroll
        for (int n = 0; n < 4; ++n)
          acc[m][n] = __builtin_amdgcn_mfma_f32_16x16x32_bf16(a[m], b[n], acc[m][n], 0, 0, 0);
    }
  }
  const float S = 65536.0f, IS = 1.0f / 65536.0f;
  int lr = (lane >> 4) * 4;
  int lc = lane & 15;
#pragma unroll
  for (int n = 0; n < 4; ++n) {
    int gcol = c0 + wc * 64 + n * 16 + lc;
    float bq = rintf(bias[gcol] * S) * IS;
#pragma unroll
    for (int m = 0; m < 4; ++m) {
      int grow = r0 + wr * 64 + m * 16 + lr;
      float* outp = C + (size_t)grow * N_DIM + gcol;
#pragma unroll
      for (int r = 0; r < 4; ++r) {
        float t = rintf(acc[m][n][r] * S) * IS + bq;
        t = t > 0.0f ? t : 0.0f;
        outp[(size_t)r * N_DIM] = t;
      }
    }
  }
}

extern "C" void kernel_launch(void* const* d_in, const int* in_sizes, int n_in,
                              void* d_out, int out_size, void* d_ws, size_t ws_size,
                              hipStream_t stream) {
  const float* x = (const float*)d_in[0];
  const float* w = (const float*)d_in[1];
  const float* b = (const float*)d_in[2];
  float* out = (float*)d_out;

  size_t needB = (size_t)K_DIM * N_DIM * sizeof(unsigned short);

  if (ws_size >= needB) {
    unsigned short* Btbf = (unsigned short*)d_ws;
    prep_kernel<<<4096, 256, 0, stream>>>(w, Btbf);
    gemm8_kernel<<<256, 512, 0, stream>>>(x, Btbf, b, out);
  } else {
    gemm_fb_kernel<<<dim3(N_DIM / 128, M_DIM / 128), 256, 0, stream>>>(x, w, b, out);
  }
}

// Round 16
// 86.778 us; speedup vs baseline: 1.1140x; 1.1131x over previous
//
#include <hip/hip_runtime.h>
#include <hip/hip_bf16.h>
#include <stdint.h>

#define M_DIM 2048
#define N_DIM 4096
#define K_DIM 4096

#define NT 64  // K tiles of 64

typedef short short8 __attribute__((ext_vector_type(8)));
typedef float f32x4 __attribute__((ext_vector_type(4)));

typedef __attribute__((address_space(1))) unsigned int gu32;
typedef __attribute__((address_space(3))) unsigned int lu32;

// f32 -> bf16 round-to-nearest-even
__device__ static inline unsigned short f32_to_bf16(float f) {
  union { float f; unsigned int u; } v; v.f = f;
  unsigned int u = v.u;
  u += 0x7FFFu + ((u >> 16) & 1u);
  return (unsigned short)(u >> 16);
}

// ---- fused prep: blocks [0,4096) convert x; [4096,8192) transpose+convert w ----
__global__ void prep_kernel(const float* __restrict__ x, unsigned short* __restrict__ xa,
                            const float* __restrict__ wsrc, unsigned short* __restrict__ wt) {
  __shared__ unsigned short tile[64][64 + 8];
  int bid = blockIdx.x;
  int t = threadIdx.x;
  if (bid < 4096) {
    size_t i = ((size_t)bid * 256 + t) * 8;
    f32x4 a = *(const f32x4*)(x + i);
    f32x4 b = *(const f32x4*)(x + i + 4);
    short8 o;
    o[0] = (short)f32_to_bf16(a[0]); o[1] = (short)f32_to_bf16(a[1]);
    o[2] = (short)f32_to_bf16(a[2]); o[3] = (short)f32_to_bf16(a[3]);
    o[4] = (short)f32_to_bf16(b[0]); o[5] = (short)f32_to_bf16(b[1]);
    o[6] = (short)f32_to_bf16(b[2]); o[7] = (short)f32_to_bf16(b[3]);
    *(short8*)(xa + i) = o;
    return;
  }
  int b2 = bid - 4096;
  int bn = (b2 & 63) * 64;  // n block
  int bk = (b2 >> 6) * 64;  // k block
  int c4 = (t & 15) * 4;
  int r0 = t >> 4;
#pragma unroll
  for (int p = 0; p < 4; ++p) {
    int r = r0 + p * 16;
    f32x4 v = *(const f32x4*)(wsrc + (size_t)(bk + r) * N_DIM + bn + c4);
    tile[c4 + 0][r] = f32_to_bf16(v[0]);
    tile[c4 + 1][r] = f32_to_bf16(v[1]);
    tile[c4 + 2][r] = f32_to_bf16(v[2]);
    tile[c4 + 3][r] = f32_to_bf16(v[3]);
  }
  __syncthreads();
  int orow = t >> 2;
  int oc = (t & 3) * 16;
  short8 lo, hi;
#pragma unroll
  for (int j = 0; j < 8; ++j) {
    lo[j] = (short)tile[orow][oc + j];
    hi[j] = (short)tile[orow][oc + 8 + j];
  }
  unsigned short* op = wt + (size_t)(bn + orow) * K_DIM + bk + oc;
  *(short8*)(op) = lo;
  *(short8*)(op + 8) = hi;
}

// ====== GEMM (final, = round 13 best): merged body, no setprio ======
// BM=128, BN=256, BK=64. 512 threads = 8 waves (2M x 4N), wave tile 64x64.
// LDS: 3 sides x 48KB. Side t%3; stage t+2 into (t-1)%3 during body t.
// ONE sync point per tile: {vmcnt(6) lgkmcnt(0); sched_barrier; s_barrier},
// merged body {16 ds_read + 6 global_load_lds + 32 MFMA} -- compiler
// interleaves reads and MFMAs (68.2us GEMM = 1007 TF, MfmaUtil 41%).
// Ledger R3-R15: setprio removal +6% (acts as unwanted compile-time fence);
// barrier count, traffic cuts, B-direct, K-split, 2 blocks/CU, SGB pinning,
// free-run windows, 32x32 shape, wave stagger, A-fusion (x2) all null or
// negative. Structure is at the chip-filling plain-HIP ceiling for M=2048.

__global__ __launch_bounds__(512) void gemm8_kernel(
    const unsigned short* __restrict__ A, const unsigned short* __restrict__ Bt,
    const float* __restrict__ bias, float* __restrict__ C) {
  __shared__ unsigned short smA[3 * 24576];  // 147456 B
  char* smemc = (char*)&smA[0];

  const int tid = threadIdx.x;
  const int lane = tid & 63;
  const int w = tid >> 6;
  const int wm = w >> 2, wn = w & 3;

  // 8x4 region remap for L2 locality (bijective over 256 blocks)
  const int id = blockIdx.x;
  const int x = id & 7, j = id >> 3;
  const int by = ((x >> 2) << 3) + (j >> 2);
  const int bx = ((x & 3) << 2) + (j & 3);
  const int r0 = by * 128, c0 = bx * 256;

  // ---- staging precompute (pre-swizzled global source, linear LDS dest) ----
  const int l8 = lane >> 3, l7 = lane & 7;
  const int chunkE = ((l7 ^ l8) << 3);  // swizzled k-chunk (bf16 elems), row&7 == l8
  const unsigned short* Ag = A + (size_t)(r0 + w * 16 + l8) * K_DIM + chunkE;
  const unsigned short* Bg = Bt + (size_t)(c0 + w * 32 + l8) * K_DIM + chunkE;
  const int aL0 = w * 2048;          // byte offset of wave's A chunk within side
  const int bL0 = 16384 + w * 4096;  // byte offset of wave's B chunk within side

#define GL(gp, ldsoff) __builtin_amdgcn_global_load_lds((gu32*)(gp), (lu32*)(smemc + (ldsoff)), 16, 0, 0)
#define STAGE_ALL(t, sb)                                               \
  do {                                                                 \
    GL(Ag + (size_t)(t) * 64, (sb) + aL0);                             \
    GL(Ag + (size_t)(t) * 64 + 8 * (size_t)K_DIM, (sb) + aL0 + 1024);  \
    GL(Bg + (size_t)(t) * 64, (sb) + bL0);                             \
    GL(Bg + (size_t)(t) * 64 + 8 * (size_t)K_DIM, (sb) + bL0 + 1024);  \
    GL(Bg + (size_t)(t) * 64 + 16 * (size_t)K_DIM, (sb) + bL0 + 2048); \
    GL(Bg + (size_t)(t) * 64 + 24 * (size_t)K_DIM, (sb) + bL0 + 3072); \
  } while (0)

  // ---- fragment-read precompute (ushort units within side) ----
  const int l15 = lane & 15, hi = lane >> 4;
  const int aR = (wm * 64 + l15) * 64;         // A row base
  const int bR = 8192 + (wn * 64 + l15) * 64;  // B row base (B region at 16KB)
  const int slot0 = ((hi ^ l7) << 3);          // ks=0: chunk hi at slot hi^(row&7)
  const int slot1 = (((4 + hi) ^ l7) << 3);    // ks=1: chunk 4+hi

  f32x4 acc[4][4] = {};

  // prologue: stage tiles 0 and 1
  STAGE_ALL(0, 0);
  STAGE_ALL(1, 49152);

  int cs = 0;  // side of tile t
  for (int t = 0; t < NT; ++t) {
    const int sE = cs * 24576;                       // compute side (ushorts)
    const int stB = (cs == 0 ? 2 : cs - 1) * 49152;  // stage side (bytes)
    const bool doStage = (t + 2) < NT;

    // single sync point per tile: my loads for tile t landed (vmcnt),
    // my side-(t-1) ds_reads complete (lgkmcnt), publish to all waves.
    if (t < NT - 1) asm volatile("s_waitcnt vmcnt(6) lgkmcnt(0)" ::: "memory");
    else            asm volatile("s_waitcnt vmcnt(0) lgkmcnt(0)" ::: "memory");
    __builtin_amdgcn_sched_barrier(0);
    asm volatile("s_barrier" ::: "memory");

    // -------- merged body: reads + stage + MFMA, compiler-interleaved ----
    short8 a0[4], b0[4], a1[4], b1[4];
#pragma unroll
    for (int m = 0; m < 4; ++m) a0[m] = *(const short8*)(smA + sE + aR + m * 1024 + slot0);
#pragma unroll
    for (int n = 0; n < 4; ++n) b0[n] = *(const short8*)(smA + sE + bR + n * 1024 + slot0);
    if (doStage) STAGE_ALL(t + 2, stB);
#pragma unroll
    for (int m = 0; m < 4; ++m) a1[m] = *(const short8*)(smA + sE + aR + m * 1024 + slot1);
#pragma unroll
    for (int n = 0; n < 4; ++n) b1[n] = *(const short8*)(smA + sE + bR + n * 1024 + slot1);

#pragma unroll
    for (int m = 0; m < 4; ++m)
#pragma unroll
      for (int n = 0; n < 4; ++n)
        acc[m][n] = __builtin_amdgcn_mfma_f32_16x16x32_bf16(a0[m], b0[n], acc[m][n], 0, 0, 0);
#pragma unroll
    for (int m = 0; m < 4; ++m)
#pragma unroll
      for (int n = 0; n < 4; ++n)
        acc[m][n] = __builtin_amdgcn_mfma_f32_16x16x32_bf16(a1[m], b1[n], acc[m][n], 0, 0, 0);

    cs = (cs == 2) ? 0 : cs + 1;
  }

  // ---- epilogue: fxp(y) + fxp(b), relu ----
  const float S = 65536.0f, IS = 1.0f / 65536.0f;
  const int lr = hi * 4;  // C/D: row=(lane>>4)*4+reg, col=lane&15
#pragma unroll
  for (int n = 0; n < 4; ++n) {
    int gcol = c0 + wn * 64 + n * 16 + l15;
    float bq = rintf(bias[gcol] * S) * IS;
#pragma unroll
    for (int m = 0; m < 4; ++m) {
      int grow = r0 + wm * 64 + m * 16 + lr;
      float* outp = C + (size_t)grow * N_DIM + gcol;
#pragma unroll
      for (int r = 0; r < 4; ++r) {
        float t = rintf(acc[m][n][r] * S) * IS + bq;
        t = t > 0.0f ? t : 0.0f;
        outp[(size_t)r * N_DIM] = t;
      }
    }
  }
#undef GL
#undef STAGE_ALL
}

// ---- fallback (small workspace): round-1 reg-staged kernel ----
__global__ __launch_bounds__(256, 2) void gemm_fb_kernel(
    const float* __restrict__ Xf, const float* __restrict__ Wf,
    const float* __restrict__ bias, float* __restrict__ C) {
  __shared__ unsigned short As[128][64];
  __shared__ unsigned short Bs[128][64];
  int tid = threadIdx.x;
  int lane = tid & 63;
  int wid = tid >> 6;
  int wr = wid >> 1, wc = wid & 1;
  int r0 = blockIdx.y * 128;
  int c0 = blockIdx.x * 128;
  f32x4 acc[4][4] = {};
  for (int kt = 0; kt < K_DIM / 64; ++kt) {
    __syncthreads();
    int ar = tid >> 1;
    int ac = (tid & 1) * 32;
    const float* xp = Xf + (size_t)(r0 + ar) * K_DIM + kt * 64 + ac;
#pragma unroll
    for (int jj = 0; jj < 8; ++jj) {
      f32x4 v = *(const f32x4*)(xp + jj * 4);
      As[ar][ac + jj * 4 + 0] = f32_to_bf16(v[0]);
      As[ar][ac + jj * 4 + 1] = f32_to_bf16(v[1]);
      As[ar][ac + jj * 4 + 2] = f32_to_bf16(v[2]);
      As[ar][ac + jj * 4 + 3] = f32_to_bf16(v[3]);
    }
    int bk_ = tid >> 2;
    int bc = (tid & 3) * 32;
    const float* wp = Wf + (size_t)(kt * 64 + bk_) * N_DIM + c0 + bc;
#pragma unroll
    for (int jj = 0; jj < 8; ++jj) {
      f32x4 v = *(const f32x4*)(wp + jj * 4);
      Bs[bc + jj * 4 + 0][bk_] = f32_to_bf16(v[0]);
      Bs[bc + jj * 4 + 1][bk_] = f32_to_bf16(v[1]);
      Bs[bc + jj * 4 + 2][bk_] = f32_to_bf16(v[2]);
      Bs[bc + jj * 4 + 3][bk_] = f32_to_bf16(v[3]);
    }
    __syncthreads();
#pragma unroll
    for (int ks = 0; ks < 2; ++ks) {
      int co = ks * 32 + (lane >> 4) * 8;
      int rA = wr * 64 + (lane & 15);
      int rB = wc * 64 + (lane & 15);
      short8 a[4], b[4];
#pragma unroll
      for (int m = 0; m < 4; ++m) a[m] = *(const short8*)&As[rA + m * 16][co];
#pragma unroll
      for (int n = 0; n < 4; ++n) b[n] = *(const short8*)&Bs[rB + n * 16][co];
#pragma unroll
      for (int m = 0; m < 4; ++m)
#pragma unroll
        for (int n = 0; n < 4; ++n)
          acc[m][n] = __builtin_amdgcn_mfma_f32_16x16x32_bf16(a[m], b[n], acc[m][n], 0, 0, 0);
    }
  }
  const float S = 65536.0f, IS = 1.0f / 65536.0f;
  int lr = (lane >> 4) * 4;
  int lc = lane & 15;
#pragma unroll
  for (int n = 0; n < 4; ++n) {
    int gcol = c0 + wc * 64 + n * 16 + lc;
    float bq = rintf(bias[gcol] * S) * IS;
#pragma unroll
    for (int m = 0; m < 4; ++m) {
      int grow = r0 + wr * 64 + m * 16 + lr;
      float* outp = C + (size_t)grow * N_DIM + gcol;
#pragma unroll
      for (int r = 0; r < 4; ++r) {
        float t = rintf(acc[m][n][r] * S) * IS + bq;
        t = t > 0.0f ? t : 0.0f;
        outp[(size_t)r * N_DIM] = t;
      }
    }
  }
}

extern "C" void kernel_launch(void* const* d_in, const int* in_sizes, int n_in,
                              void* d_out, int out_size, void* d_ws, size_t ws_size,
                              hipStream_t stream) {
  const float* x = (const float*)d_in[0];
  const float* w = (const float*)d_in[1];
  const float* b = (const float*)d_in[2];
  float* out = (float*)d_out;

  size_t needA = (size_t)M_DIM * K_DIM * sizeof(unsigned short);
  size_t needB = (size_t)K_DIM * N_DIM * sizeof(unsigned short);

  if (ws_size >= needA + needB) {
    unsigned short* Abf = (unsigned short*)d_ws;
    unsigned short* Btbf = (unsigned short*)((char*)d_ws + needA);
    prep_kernel<<<8192, 256, 0, stream>>>(x, Abf, w, Btbf);
    gemm8_kernel<<<256, 512, 0, stream>>>(Abf, Btbf, b, out);
  } else {
    gemm_fb_kernel<<<dim3(N_DIM / 128, M_DIM / 128), 256, 0, stream>>>(x, w, b, out);
  }
}